// Round 1
// baseline (330.472 us; speedup 1.0000x reference)
//
#include <hip/hip_runtime.h>

typedef unsigned short u16;
typedef unsigned int u32;

// ---------- bf16 helpers (bit-level, no hip_bf16 API dependence) ----------
__device__ __forceinline__ float bf2f(u16 h) {
  union { u32 u; float f; } v; v.u = ((u32)h) << 16; return v.f;
}
__device__ __forceinline__ u16 f2bf(float f) {
  union { float f; u32 u; } v; v.f = f;
  u32 r = v.u + 0x7FFFu + ((v.u >> 16) & 1u);   // round-to-nearest-even
  return (u16)(r >> 16);
}
__device__ __forceinline__ float ldw(const void* p, int i, bool bf) {
  return bf ? bf2f(((const u16*)p)[i]) : ((const float*)p)[i];
}
// Detect whether a weight buffer is bf16 or fp32. Weights are uniform in
// [-1/sqrt(fan_in), +1/sqrt(fan_in)] with fan_in >= 72 -> |w| <= 0.118.
// If the buffer is fp32, every even u16 is low-mantissa junk which, read as
// bf16, exceeds 0.125 with ~52% probability per element -> P(all 32 pass) ~ 6e-11.
__device__ __forceinline__ bool detect_bf16(const void* w1) {
  const u16* p = (const u16*)w1;
  bool ok = true;
  for (int k = 0; k < 64; ++k) {
    float v = bf2f(p[k]);
    ok &= (fabsf(v) <= 0.125f);
  }
  return ok;
}

// ---------- workspace layout (floats) ----------
#define WS_WP    0      // [5][9][36]   gather table, piece 4 = zeros (border dummy)
#define WS_T     1620   // [4]x580, [16][36]  ac-term + bias folded in
#define WS_W2    3940   // [16][32]
#define WS_B2    4452   // [16]
#define WS_WO1   4468   // [16][16]
#define WS_BO1   4724   // [16]
#define WS_WO2   4740   // [8][16]
#define WS_P2    4868   // [4][8]  w_ob2[o][16+p] transposed -> [p][o]
#define WS_BO2   4900   // [8]
#define WS_WR    4908   // [8][16]
#define WS_BR    5036   // [8]
#define WS_FCR   5044   // [16 cells][36]: [c][k*8+ch] = fc_r[k][ch*16+c]
#define WS_FBR   5620   // [4]
#define WS_WG    5624   // [8][16]
#define WS_BG    5752   // [8]
#define WS_FCG   5760   // [16][36]
#define WS_FBG   6336   // [4]
#define WS_FLAG  6340

// ---------- prep: convert/reorganize weights into fp32 tables ----------
__global__ __launch_bounds__(256) void dw_prep(
    const void* w1, const void* b1, const void* w2, const void* b2,
    const void* wo1, const void* bo1, const void* wo2, const void* bo2,
    const void* wr, const void* br, const void* fcr, const void* fbr,
    const void* wg, const void* bg, const void* fcg, const void* fbg,
    float* ws) {
  const int tid = threadIdx.x;
  const bool bf = detect_bf16(w1);

  // WP[p][pos][o]: w1[o][p][ky][kx]; p==4 -> 0 (invalid-neighbor dummy)
  for (int t = tid; t < 1620; t += 256) {
    int p = t / 324, r = t % 324, pos = r / 36, o = r % 36;
    float v = 0.f;
    if (o < 32 && p < 4) v = ldw(w1, ((o * 8 + p) * 3 + pos / 3) * 3 + (pos % 3), bf);
    ws[WS_WP + t] = v;
  }
  // T[a][cell][o] = b1[o] + sum over valid 3x3 taps of w1[o][4+a][dy][dx]
  for (int t = tid; t < 2304; t += 256) {
    int a = t / 576, r = t % 576, cell = r / 36, o = r % 36;
    float v = 0.f;
    if (o < 32) {
      int ci = cell >> 2, cj = cell & 3;
      float s = ldw(b1, o, bf);
      for (int dy = 0; dy < 3; ++dy)
        for (int dx = 0; dx < 3; ++dx) {
          int ni = ci + dy - 1, nj = cj + dx - 1;
          if (ni >= 0 && ni < 4 && nj >= 0 && nj < 4)
            s += ldw(w1, ((o * 8 + 4 + a) * 3 + dy) * 3 + dx, bf);
        }
      v = s;
    }
    ws[WS_T + a * 580 + cell * 36 + o] = v;
  }
  for (int t = tid; t < 512; t += 256) ws[WS_W2 + t] = ldw(w2, t, bf);
  for (int t = tid; t < 16;  t += 256) ws[WS_B2 + t] = ldw(b2, t, bf);
  for (int t = tid; t < 256; t += 256) ws[WS_WO1 + t] = ldw(wo1, t, bf);
  for (int t = tid; t < 16;  t += 256) ws[WS_BO1 + t] = ldw(bo1, t, bf);
  for (int t = tid; t < 128; t += 256) ws[WS_WO2 + t] = ldw(wo2, (t / 16) * 20 + (t % 16), bf);
  for (int t = tid; t < 32;  t += 256) ws[WS_P2 + t] = ldw(wo2, (t % 8) * 20 + 16 + t / 8, bf);
  for (int t = tid; t < 8;   t += 256) ws[WS_BO2 + t] = ldw(bo2, t, bf);
  for (int t = tid; t < 128; t += 256) ws[WS_WR + t] = ldw(wr, t, bf);
  for (int t = tid; t < 8;   t += 256) ws[WS_BR + t] = ldw(br, t, bf);
  for (int t = tid; t < 576; t += 256) {
    int cell = t / 36, kk = t % 36;
    ws[WS_FCR + t] = (kk < 32) ? ldw(fcr, (kk / 8) * 128 + (kk % 8) * 16 + cell, bf) : 0.f;
  }
  for (int t = tid; t < 4;   t += 256) ws[WS_FBR + t] = ldw(fbr, t, bf);
  for (int t = tid; t < 128; t += 256) ws[WS_WG + t] = ldw(wg, t, bf);
  for (int t = tid; t < 8;   t += 256) ws[WS_BG + t] = ldw(bg, t, bf);
  for (int t = tid; t < 576; t += 256) {
    int cell = t / 36, kk = t % 36;
    ws[WS_FCG + t] = (kk < 32) ? ldw(fcg, (kk / 8) * 128 + (kk % 8) * 16 + cell, bf) : 0.f;
  }
  for (int t = tid; t < 4;   t += 256) ws[WS_FBG + t] = ldw(fbg, t, bf);
  if (tid == 0) ws[WS_FLAG] = bf ? 1.f : 0.f;
}

// ---------- main kernel: 1 lane = 1 cell, 16 elements / 256-thread block ----------
__global__ __launch_bounds__(256) void dw_main(
    const int* __restrict__ ob, const int* __restrict__ ac,
    const float* __restrict__ g, void* __restrict__ outp, int B) {
  __shared__ float sWP[1620];
  __shared__ float sT[2320];
  __shared__ float sFr[576];
  __shared__ float sFg[576];
  __shared__ float sP2[32];
  __shared__ int sPiece[256];

  const int tid = threadIdx.x;
  for (int t = tid; t < 1620; t += 256) sWP[t] = g[WS_WP + t];
  for (int t = tid; t < 2320; t += 256) sT[t] = g[WS_T + t];
  for (int t = tid; t < 576; t += 256) sFr[t] = g[WS_FCR + t];
  for (int t = tid; t < 576; t += 256) sFg[t] = g[WS_FCG + t];
  if (tid < 32) sP2[tid] = g[WS_P2 + tid];

  const int el = tid >> 4;       // element within block
  const int c  = tid & 15;       // cell 0..15
  const int e  = blockIdx.x * 16 + el;
  const bool act = (e < B);
  const int eC = act ? e : (B - 1);
  const int piece = ob[eC * 16 + c];
  sPiece[tid] = piece;
  const int a = ac[eC];
  __syncthreads();

  const bool obf = g[WS_FLAG] > 0.5f;
  const int ci = c >> 2, cj = c & 3;

  // ---- conv3x3 via gather-add ----
  float z[32];
  {
    const float* tp = &sT[a * 580 + c * 36];
#pragma unroll
    for (int k = 0; k < 32; k += 4) {
      float4 v = *(const float4*)&tp[k];
      z[k] = v.x; z[k + 1] = v.y; z[k + 2] = v.z; z[k + 3] = v.w;
    }
  }
#pragma unroll
  for (int pos = 0; pos < 9; ++pos) {
    const int dy = pos / 3 - 1, dx = pos % 3 - 1;
    const int ni = ci + dy, nj = cj + dx;
    const bool valid = ((unsigned)ni < 4u) && ((unsigned)nj < 4u);
    const int p = valid ? sPiece[(el << 4) + ni * 4 + nj] : 4;
    const float* wp = &sWP[(p * 9 + pos) * 36];
#pragma unroll
    for (int k = 0; k < 32; k += 4) {
      float4 v = *(const float4*)&wp[k];
      z[k] += v.x; z[k + 1] += v.y; z[k + 2] += v.z; z[k + 3] += v.w;
    }
  }
#pragma unroll
  for (int k = 0; k < 32; ++k) z[k] = fmaxf(z[k], 0.f);

  // ---- conv1x1 32->16 (uniform weights -> scalar loads) ----
  float x16[16];
#pragma unroll
  for (int o = 0; o < 16; ++o) {
    float acc = g[WS_B2 + o];
#pragma unroll
    for (int ic = 0; ic < 32; ++ic) acc = fmaf(g[WS_W2 + o * 32 + ic], z[ic], acc);
    x16[o] = fmaxf(acc, 0.f);
  }

  // ---- ob head: 16->16 relu, then (16+onehot)->8 ----
  float n16[16];
#pragma unroll
  for (int o = 0; o < 16; ++o) {
    float acc = g[WS_BO1 + o];
#pragma unroll
    for (int ic = 0; ic < 16; ++ic) acc = fmaf(g[WS_WO1 + o * 16 + ic], x16[ic], acc);
    n16[o] = fmaxf(acc, 0.f);
  }
  float no[8];
  {
    float4 v0 = *(const float4*)&sP2[piece * 8];
    float4 v1 = *(const float4*)&sP2[piece * 8 + 4];
    float pc[8] = {v0.x, v0.y, v0.z, v0.w, v1.x, v1.y, v1.z, v1.w};
#pragma unroll
    for (int o = 0; o < 8; ++o) {
      float acc = g[WS_BO2 + o] + pc[o];
#pragma unroll
      for (int ic = 0; ic < 16; ++ic) acc = fmaf(g[WS_WO2 + o * 16 + ic], n16[ic], acc);
      no[o] = acc;
    }
  }
  if (act) {
    size_t loc = (size_t)e * 64 + c * 4;
    size_t scl = (size_t)B * 64 + loc;
    if (obf) {
      u16* o16 = (u16*)outp;
      u32 a0 = (u32)f2bf(no[0]) | ((u32)f2bf(no[1]) << 16);
      u32 a1 = (u32)f2bf(no[2]) | ((u32)f2bf(no[3]) << 16);
      u32 a2 = (u32)f2bf(no[4]) | ((u32)f2bf(no[5]) << 16);
      u32 a3 = (u32)f2bf(no[6]) | ((u32)f2bf(no[7]) << 16);
      *(uint2*)(o16 + loc) = make_uint2(a0, a1);
      *(uint2*)(o16 + scl) = make_uint2(a2, a3);
    } else {
      float* of = (float*)outp;
      *(float4*)(of + loc) = make_float4(no[0], no[1], no[2], no[3]);
      *(float4*)(of + scl) = make_float4(no[4], no[5], no[6], no[7]);
    }
  }

  // ---- reward head ----
  float pk[4];
  {
    float r8[8];
#pragma unroll
    for (int o = 0; o < 8; ++o) {
      float acc = g[WS_BR + o];
#pragma unroll
      for (int ic = 0; ic < 16; ++ic) acc = fmaf(g[WS_WR + o * 16 + ic], x16[ic], acc);
      r8[o] = fmaxf(acc, 0.f);
    }
#pragma unroll
    for (int k = 0; k < 4; ++k) {
      float4 w0 = *(const float4*)&sFr[c * 36 + k * 8];
      float4 w1 = *(const float4*)&sFr[c * 36 + k * 8 + 4];
      pk[k] = w0.x * r8[0] + w0.y * r8[1] + w0.z * r8[2] + w0.w * r8[3]
            + w1.x * r8[4] + w1.y * r8[5] + w1.z * r8[6] + w1.w * r8[7];
    }
  }
#pragma unroll
  for (int m = 1; m < 16; m <<= 1) {
#pragma unroll
    for (int k = 0; k < 4; ++k) pk[k] += __shfl_xor(pk[k], m, 64);
  }
  if (act && c == 0) {
    float r0 = pk[0] + g[WS_FBR + 0], r1 = pk[1] + g[WS_FBR + 1];
    float r2 = pk[2] + g[WS_FBR + 2], r3 = pk[3] + g[WS_FBR + 3];
    if (obf) {
      u16* o16 = (u16*)outp;
      *(u32*)(o16 + ((size_t)B * 128 + e * 2)) = (u32)f2bf(r0) | ((u32)f2bf(r1) << 16);
      *(u32*)(o16 + ((size_t)B * 130 + e * 2)) = (u32)f2bf(r2) | ((u32)f2bf(r3) << 16);
    } else {
      float* of = (float*)outp;
      *(float2*)(of + ((size_t)B * 128 + e * 2)) = make_float2(r0, r1);
      *(float2*)(of + ((size_t)B * 130 + e * 2)) = make_float2(r2, r3);
    }
  }

  // ---- go head ----
  {
    float g8[8];
#pragma unroll
    for (int o = 0; o < 8; ++o) {
      float acc = g[WS_BG + o];
#pragma unroll
      for (int ic = 0; ic < 16; ++ic) acc = fmaf(g[WS_WG + o * 16 + ic], x16[ic], acc);
      g8[o] = fmaxf(acc, 0.f);
    }
#pragma unroll
    for (int k = 0; k < 4; ++k) {
      float4 w0 = *(const float4*)&sFg[c * 36 + k * 8];
      float4 w1 = *(const float4*)&sFg[c * 36 + k * 8 + 4];
      pk[k] = w0.x * g8[0] + w0.y * g8[1] + w0.z * g8[2] + w0.w * g8[3]
            + w1.x * g8[4] + w1.y * g8[5] + w1.z * g8[6] + w1.w * g8[7];
    }
  }
#pragma unroll
  for (int m = 1; m < 16; m <<= 1) {
#pragma unroll
    for (int k = 0; k < 4; ++k) pk[k] += __shfl_xor(pk[k], m, 64);
  }
  if (act && c == 0) {
    float r0 = pk[0] + g[WS_FBG + 0], r1 = pk[1] + g[WS_FBG + 1];
    float r2 = pk[2] + g[WS_FBG + 2], r3 = pk[3] + g[WS_FBG + 3];
    if (obf) {
      u16* o16 = (u16*)outp;
      *(u32*)(o16 + ((size_t)B * 132 + e * 2)) = (u32)f2bf(r0) | ((u32)f2bf(r1) << 16);
      *(u32*)(o16 + ((size_t)B * 134 + e * 2)) = (u32)f2bf(r2) | ((u32)f2bf(r3) << 16);
    } else {
      float* of = (float*)outp;
      *(float2*)(of + ((size_t)B * 132 + e * 2)) = make_float2(r0, r1);
      *(float2*)(of + ((size_t)B * 134 + e * 2)) = make_float2(r2, r3);
    }
  }
}

extern "C" void kernel_launch(void* const* d_in, const int* in_sizes, int n_in,
                              void* d_out, int out_size, void* d_ws, size_t ws_size,
                              hipStream_t stream) {
  const int* ob = (const int*)d_in[0];
  const int* ac = (const int*)d_in[1];
  float* ws = (float*)d_ws;
  const int B = in_sizes[1];

  hipLaunchKernelGGL(dw_prep, dim3(1), dim3(256), 0, stream,
                     d_in[2], d_in[3], d_in[4], d_in[5], d_in[6], d_in[7],
                     d_in[8], d_in[9], d_in[10], d_in[11], d_in[12], d_in[13],
                     d_in[14], d_in[15], d_in[16], d_in[17], ws);

  const int nb = (B + 15) / 16;
  hipLaunchKernelGGL(dw_main, dim3(nb), dim3(256), 0, stream, ob, ac, ws, d_out, B);
}

// Round 2
// 79.494 us; speedup vs baseline: 4.1572x; 4.1572x over previous
//
#include <hip/hip_runtime.h>
#include <hip/hip_bf16.h>

typedef unsigned short u16;
typedef unsigned int u32;
typedef unsigned long long u64;

typedef __attribute__((ext_vector_type(8))) short vbf8;    // 8 bf16 (4 VGPRs)
typedef __attribute__((ext_vector_type(16))) float vf16;   // MFMA acc

// ---------------- workspace layout (u32 units) ----------------
#define A1_OFF   0      // [5 kb][64 lane][4]  stage1 weights (one-hot K=80)
#define A2_OFF   1280   // [3 kb][64][4]       conv2 (K: 32 z-chan pi-order + bias col)
#define A3_OFF   2048   // [2 kb][64][4]       heads [Wob1;Wr;Wg] (K=16 sigma + bias col)
#define A4_OFF   2560   // [2 kb][64][4]       ob2 (K=16 sigma + bias + 4 piece cols)
#define FR_OFF   3072   // [4k][2hi][16cell][4ch] f32
#define FG_OFF   3584   // same
#define FB_OFF   4096   // fbr[4], fbg[4]
#define FLAG_OFF 4104   // u32 bf16-flag

// ---------------- bf16 bit helpers ----------------
__device__ __forceinline__ float bf2f(u16 h){ union{u32 u; float f;} v; v.u=((u32)h)<<16; return v.f; }
__device__ __forceinline__ u16 f2bf(float f){ union{float f; u32 u;} v; v.f=f; u32 r=v.u+0x7FFFu+((v.u>>16)&1u); return (u16)(r>>16); }
__device__ __forceinline__ float ldw(const void* p,int i,bool bf){ return bf? bf2f(((const u16*)p)[i]) : ((const float*)p)[i]; }

__device__ __forceinline__ bool detect_bf16(const void* w1){
  const u16* p=(const u16*)w1; bool ok=true;
  for(int k=0;k<64;++k){ float v=bf2f(p[k]); ok &= (fabsf(v)<=0.125f); }
  return ok;
}

// channel permutations matching the MFMA D-register order per lane
__device__ __constant__ int PI[32] = {0,1,2,3,8,9,10,11,4,5,6,7,12,13,14,15,
                                      16,17,18,19,24,25,26,27,20,21,22,23,28,29,30,31};

// ---------------- prep: build per-lane A-fragments + fc tables ----------------
__global__ __launch_bounds__(256) void dw_prep(
    const void* w1, const void* b1, const void* w2, const void* b2,
    const void* wo1, const void* bo1, const void* wo2, const void* bo2,
    const void* wr, const void* br, const void* fcr, const void* fbr,
    const void* wg, const void* bg, const void* fcg, const void* fbg,
    u32* wsu){
  const int tid = threadIdx.x;
  const bool bf = detect_bf16(w1);
  float* wsf = (float*)wsu;

  // A1: K one-hot space. qd=K>>2, q=K&3. qd<9: piece(pos=qd); qd<18: action(pos=qd-9);
  // qd==18,q==0: bias; else 0.
  for (int t=tid; t<1280; t+=256){
    int kb=t>>8, l=(t>>2)&63, r=t&3, hi=l>>5, row=l&31;
    int K0=kb*16+hi*8+2*r; u32 w=0;
    for (int s=0;s<2;++s){
      int K=K0+s, qd=K>>2, q=K&3; float v=0.f;
      if (qd<9)        v = ldw(w1, row*72 + q*9 + qd, bf);
      else if (qd<18)  v = ldw(w1, row*72 + (4+q)*9 + (qd-9), bf);
      else if (qd==18 && q==0) v = ldw(b1, row, bf);
      w |= ((u32)f2bf(v)) << (16*s);
    }
    wsu[A1_OFF+t]=w;
  }
  // A2: K<32: w2[row][PI[K]] (row<16); K==32: b2[row]
  for (int t=tid; t<768; t+=256){
    int kb=t>>8, l=(t>>2)&63, r=t&3, hi=l>>5, row=l&31;
    int K0=kb*16+hi*8+2*r; u32 w=0;
    for (int s=0;s<2;++s){
      int K=K0+s; float v=0.f;
      if (K<32){ if(row<16) v=ldw(w2, row*32+PI[K], bf); }
      else if (K==32 && row<16) v=ldw(b2, row, bf);
      w |= ((u32)f2bf(v)) << (16*s);
    }
    wsu[A2_OFF+t]=w;
  }
  // A3: rows 0-15 Wob1, 16-23 Wr, 24-31 Wg; K<16 data (sigma=PI), K==16 bias
  for (int t=tid; t<512; t+=256){
    int kb=t>>8, l=(t>>2)&63, r=t&3, hi=l>>5, row=l&31;
    int K0=kb*16+hi*8+2*r; u32 w=0;
    for (int s=0;s<2;++s){
      int K=K0+s; float v=0.f;
      if (K<16){
        int c=PI[K];
        v = (row<16)? ldw(wo1,row*16+c,bf) : (row<24)? ldw(wr,(row-16)*16+c,bf) : ldw(wg,(row-24)*16+c,bf);
      } else if (K==16){
        v = (row<16)? ldw(bo1,row,bf) : (row<24)? ldw(br,row-16,bf) : ldw(bg,row-24,bf);
      }
      w |= ((u32)f2bf(v)) << (16*s);
    }
    wsu[A3_OFF+t]=w;
  }
  // A4: rows 0-7 Wob2; K<16 data, K==16 bias, K 17-20 piece-onehot columns
  for (int t=tid; t<512; t+=256){
    int kb=t>>8, l=(t>>2)&63, r=t&3, hi=l>>5, row=l&31;
    int K0=kb*16+hi*8+2*r; u32 w=0;
    for (int s=0;s<2;++s){
      int K=K0+s; float v=0.f;
      if (row<8){
        if (K<16)            v=ldw(wo2, row*20+PI[K], bf);
        else if (K==16)      v=ldw(bo2, row, bf);
        else if (K>=17&&K<=20) v=ldw(wo2, row*20+16+(K-17), bf);
      }
      w |= ((u32)f2bf(v)) << (16*s);
    }
    wsu[A4_OFF+t]=w;
  }
  // FC tables (fp32): [k][hi][cell][c] = fc[k][(4hi+c)*16+cell]
  for (int t=tid; t<512; t+=256){
    int k=t>>7, hi=(t>>6)&1, cell=(t>>2)&15, c=t&3;
    wsf[FR_OFF+t] = ldw(fcr, k*128+(4*hi+c)*16+cell, bf);
    wsf[FG_OFF+t] = ldw(fcg, k*128+(4*hi+c)*16+cell, bf);
  }
  for (int t=tid; t<8; t+=256) wsf[FB_OFF+t] = ldw(t<4?fbr:fbg, t&3, bf);
  if (tid==0) wsu[FLAG_OFF] = bf ? 1u : 0u;
}

// ---------------- main kernel ----------------
// neighbor info per cell: 9 x 5 bits = (valid<<4)|ncell
__host__ __device__ constexpr u64 nbgen(int c){
  u64 v=0;
  for (int pos=0; pos<9; ++pos){
    int dy=pos/3-1, dx=pos%3-1, i=c/4+dy, j=c%4+dx;
    if (i>=0&&i<4&&j>=0&&j<4) v |= ((u64)(16|(i*4+j)))<<(5*pos);
  }
  return v;
}
__device__ __constant__ u64 NB[16] = {
  nbgen(0),nbgen(1),nbgen(2),nbgen(3),nbgen(4),nbgen(5),nbgen(6),nbgen(7),
  nbgen(8),nbgen(9),nbgen(10),nbgen(11),nbgen(12),nbgen(13),nbgen(14),nbgen(15)};

__device__ __forceinline__ vf16 mfma(int4 a, int4 b, vf16 c){
  union{int4 i; vbf8 v;} ua, ub; ua.i=a; ub.i=b;
  return __builtin_amdgcn_mfma_f32_32x32x16_bf16(ua.v, ub.v, c, 0, 0, 0);
}
__device__ __forceinline__ u32 pkbf(float a, float b){
  u16 lo=__builtin_bit_cast(u16,__float2bfloat16(a));
  u16 hi=__builtin_bit_cast(u16,__float2bfloat16(b));
  return (u32)lo | ((u32)hi<<16);
}
// exact hi/lo split: hi = mantissa-truncated pair-packed, lo = bf16(residual)
__device__ __forceinline__ void split2(float a, float b, u32& wh, u32& wl){
  u32 ua=__builtin_bit_cast(u32,a), ub=__builtin_bit_cast(u32,b);
  u32 ha=ua&0xFFFF0000u, hb=ub&0xFFFF0000u;
  wh = (ha>>16) | hb;
  wl = pkbf(a-__builtin_bit_cast(float,ha), b-__builtin_bit_cast(float,hb));
}
template<int CTRL> __device__ __forceinline__ float dppadd(float x){
  int y=__builtin_amdgcn_update_dpp(0,__builtin_bit_cast(int,x),CTRL,0xF,0xF,false);
  return x+__builtin_bit_cast(float,y);
}
__device__ __forceinline__ float redsum(float x, int xaddr){
  x=dppadd<0xB1>(x); x=dppadd<0x4E>(x);   // quad_perm xor1, xor2
  x=dppadd<0x124>(x); x=dppadd<0x128>(x); // row_ror:4, row_ror:8
  int y=__builtin_amdgcn_ds_bpermute(xaddr,__builtin_bit_cast(int,x));
  return x+__builtin_bit_cast(float,y);   // xor32 (combine hi-halves)
}

__global__ __launch_bounds__(256) void dw_main(
    const int* __restrict__ ob, const int* __restrict__ ac,
    const u32* __restrict__ g, void* __restrict__ outp, int B){
  const int tid  = threadIdx.x;
  const int lane = tid & 63;
  const int hi   = lane >> 5;
  const int col  = lane & 31;
  const int c16  = col & 15;
  const int elem = col >> 4;
  const int hi2  = hi << 1;

  const int e = (((blockIdx.x<<2) + (tid>>6))<<1) + elem;
  const bool act = (e < B);
  const int eL = act ? e : 0;

  const bool obf = g[FLAG_OFF] != 0u;
  const int4* gA = (const int4*)g;
  const float4* gF = (const float4*)g;

  // weight fragments (L2-hot, identical for every wave)
  int4 A1f[5], A2f[3], A3f[2], A4f[2];
#pragma unroll
  for (int kb=0;kb<5;++kb) A1f[kb]=gA[(A1_OFF>>2)+kb*64+lane];
#pragma unroll
  for (int kb=0;kb<3;++kb) A2f[kb]=gA[(A2_OFF>>2)+kb*64+lane];
#pragma unroll
  for (int kb=0;kb<2;++kb) A3f[kb]=gA[(A3_OFF>>2)+kb*64+lane];
#pragma unroll
  for (int kb=0;kb<2;++kb) A4f[kb]=gA[(A4_OFF>>2)+kb*64+lane];

  // board (2-bit packed) + action
  const int4* obp = (const int4*)(ob + (size_t)eL*16);
  int4 o0=obp[0], o1=obp[1], o2=obp[2], o3=obp[3];
  u32 pk = (u32)o0.x | ((u32)o0.y<<2) | ((u32)o0.z<<4) | ((u32)o0.w<<6)
         | ((u32)o1.x<<8) | ((u32)o1.y<<10) | ((u32)o1.z<<12) | ((u32)o1.w<<14)
         | ((u32)o2.x<<16) | ((u32)o2.y<<18) | ((u32)o2.z<<20) | ((u32)o2.w<<22)
         | ((u32)o3.x<<24) | ((u32)o3.y<<26) | ((u32)o3.z<<28) | ((u32)o3.w<<30);
  const int a = ac[eL];
  const u64 nb = NB[c16];

  // ---- stage 1: one-hot B-fragment (K=80) ----
  int4 breg[5];
#pragma unroll
  for (int kb=0;kb<5;++kb){
    u32 w[4];
#pragma unroll
    for (int t=0;t<2;++t){
      int qd = kb*4 + hi2 + t;
      bool isact = qd>=9;
      int pos = isact ? qd-9 : qd;                 // may be 9/10 -> bits=0
      u32 bits = (u32)(nb >> (pos*5)) & 31u;
      int nc = bits & 15;
      int np = (int)((pk >> (nc<<1)) & 3u);
      int sel = isact ? a : np;
      int m = (bits & 16u) ? sel : 7;
      u64 oh = (m<4) ? (0x3F80ull << ((m&3)<<4)) : 0ull;
      u32 w0=(u32)oh, w1=(u32)(oh>>32);
      if (kb==4){                                   // qd 18/19 (hi=1): bias / zero
        if (t==0){ w0 = hi ? 0x3F80u : w0; w1 = hi ? 0u : w1; }
        else     { w0 = hi ? 0u      : w0; w1 = hi ? 0u : w1; }
      }
      w[2*t]=w0; w[2*t+1]=w1;
    }
    breg[kb]=make_int4(w[0],w[1],w[2],w[3]);
  }

  vf16 zero = {0.f,0.f,0.f,0.f,0.f,0.f,0.f,0.f,0.f,0.f,0.f,0.f,0.f,0.f,0.f,0.f};
  vf16 acc = zero;
#pragma unroll
  for (int kb=0;kb<5;++kb) acc = mfma(A1f[kb], breg[kb], acc);

  // relu + hi/lo split into conv2 B-fragments
  u32 zh[8], zl[8];
#pragma unroll
  for (int i=0;i<8;++i){
    float za=fmaxf(acc[2*i],0.f), zb=fmaxf(acc[2*i+1],0.f);
    split2(za,zb,zh[i],zl[i]);
  }
  const int4 bconst = make_int4(hi?0:0x3F80, 0, 0, 0);
  int4 B2h0=make_int4(zh[0],zh[1],zh[2],zh[3]), B2h1=make_int4(zh[4],zh[5],zh[6],zh[7]);
  int4 B2l0=make_int4(zl[0],zl[1],zl[2],zl[3]), B2l1=make_int4(zl[4],zl[5],zl[6],zl[7]);

  vf16 acc2 = mfma(A2f[0],B2h0,zero);
  acc2 = mfma(A2f[1],B2h1,acc2);
  acc2 = mfma(A2f[2],bconst,acc2);   // bias column
  acc2 = mfma(A2f[0],B2l0,acc2);
  acc2 = mfma(A2f[1],B2l1,acc2);

  // x16 (regs 0-7 valid) -> heads B-fragment
  u32 xh[4], xl[4];
#pragma unroll
  for (int i=0;i<4;++i){
    float xa=fmaxf(acc2[2*i],0.f), xb=fmaxf(acc2[2*i+1],0.f);
    split2(xa,xb,xh[i],xl[i]);
  }
  int4 B3h=make_int4(xh[0],xh[1],xh[2],xh[3]), B3l=make_int4(xl[0],xl[1],xl[2],xl[3]);
  vf16 acc3 = mfma(A3f[0],B3h,zero);
  acc3 = mfma(A3f[1],bconst,acc3);
  acc3 = mfma(A3f[0],B3l,acc3);

  // n16 (regs 0-7), r8 (8-11), g8 (12-15)
  u32 nh[4], nl[4];
#pragma unroll
  for (int i=0;i<4;++i){
    float na=fmaxf(acc3[2*i],0.f), nbv=fmaxf(acc3[2*i+1],0.f);
    split2(na,nbv,nh[i],nl[i]);
  }
  float r8[4], g8[4];
#pragma unroll
  for (int i=0;i<4;++i){ r8[i]=fmaxf(acc3[8+i],0.f); g8[i]=fmaxf(acc3[12+i],0.f); }

  // ob2: bias + piece-onehot folded into kb1
  const int p = (int)((pk >> (c16<<1)) & 3u);
  int4 B4b = make_int4(
      hi?0u:(0x3F80u | ((p==0)?0x3F800000u:0u)),
      hi?0u:(((p==1)?0x3F80u:0u) | ((p==2)?0x3F800000u:0u)),
      hi?0u:((p==3)?0x3F80u:0u), 0u);
  int4 B4h=make_int4(nh[0],nh[1],nh[2],nh[3]), B4l=make_int4(nl[0],nl[1],nl[2],nl[3]);
  vf16 acc4 = mfma(A4f[0],B4h,zero);
  acc4 = mfma(A4f[1],B4b,acc4);
  acc4 = mfma(A4f[0],B4l,acc4);

  // ---- store next_ob (hi=0: loc outs 0-3, hi=1: scale outs 4-7) ----
  if (act){
    size_t base=(size_t)e*64 + c16*4;
    size_t off = hi ? ((size_t)B*64 + base) : base;
    if (obf){
      u16* o16=(u16*)outp;
      *(uint2*)(o16+off) = make_uint2(pkbf(acc4[0],acc4[1]), pkbf(acc4[2],acc4[3]));
    } else {
      float* of=(float*)outp;
      *(float4*)(of+off) = make_float4(acc4[0],acc4[1],acc4[2],acc4[3]);
    }
  }

  // ---- fc heads (fp32) ----
  float rk[4], gk[4];
#pragma unroll
  for (int k=0;k<4;++k){
    float4 wr4 = gF[(FR_OFF>>2) + (k*2+hi)*16 + c16];
    float4 wg4 = gF[(FG_OFF>>2) + (k*2+hi)*16 + c16];
    rk[k] = wr4.x*r8[0]+wr4.y*r8[1]+wr4.z*r8[2]+wr4.w*r8[3];
    gk[k] = wg4.x*g8[0]+wg4.y*g8[1]+wg4.z*g8[2]+wg4.w*g8[3];
  }
  const int xaddr = (lane^32)<<2;
#pragma unroll
  for (int k=0;k<4;++k){ rk[k]=redsum(rk[k],xaddr); gk[k]=redsum(gk[k],xaddr); }

  if (act && c16==0 && hi==0){
    float4 fb1=gF[FB_OFF>>2], fb2=gF[(FB_OFF>>2)+1];
    float r0=rk[0]+fb1.x, r1=rk[1]+fb1.y, r2=rk[2]+fb1.z, r3=rk[3]+fb1.w;
    float g0=gk[0]+fb2.x, g1=gk[1]+fb2.y, g2=gk[2]+fb2.z, g3=gk[3]+fb2.w;
    if (obf){
      u16* o16=(u16*)outp;
      *(u32*)(o16 + (size_t)B*128 + e*2) = pkbf(r0,r1);
      *(u32*)(o16 + (size_t)B*130 + e*2) = pkbf(r2,r3);
      *(u32*)(o16 + (size_t)B*132 + e*2) = pkbf(g0,g1);
      *(u32*)(o16 + (size_t)B*134 + e*2) = pkbf(g2,g3);
    } else {
      float* of=(float*)outp;
      *(float2*)(of + (size_t)B*128 + e*2) = make_float2(r0,r1);
      *(float2*)(of + (size_t)B*130 + e*2) = make_float2(r2,r3);
      *(float2*)(of + (size_t)B*132 + e*2) = make_float2(g0,g1);
      *(float2*)(of + (size_t)B*134 + e*2) = make_float2(g2,g3);
    }
  }
}

extern "C" void kernel_launch(void* const* d_in, const int* in_sizes, int n_in,
                              void* d_out, int out_size, void* d_ws, size_t ws_size,
                              hipStream_t stream) {
  const int* ob = (const int*)d_in[0];
  const int* ac = (const int*)d_in[1];
  u32* ws = (u32*)d_ws;
  const int B = in_sizes[1];

  hipLaunchKernelGGL(dw_prep, dim3(1), dim3(256), 0, stream,
                     d_in[2], d_in[3], d_in[4], d_in[5], d_in[6], d_in[7],
                     d_in[8], d_in[9], d_in[10], d_in[11], d_in[12], d_in[13],
                     d_in[14], d_in[15], d_in[16], d_in[17], ws);

  const int nb = (B + 7) / 8;
  hipLaunchKernelGGL(dw_main, dim3(nb), dim3(256), 0, stream, ob, ac, ws, d_out, B);
}